// Round 1
// baseline (90.401 us; speedup 1.0000x reference)
//
#include <hip/hip_runtime.h>

// Focal loss: out[0]=loss_pos, out[1]=loss_neg, out[2]=count_pos, out[3]=count_neg
// Reference: ALPHA=2, FPN_POS_FACTOR=(2,1), FPN_NEG_FACTOR=(2,1), ANCHOR_POS_FACTOR={1,1}
// logit0: [8,2,64,128,128] f32, logit1: [8,2,32,64,64] f32
// prob_gt same shapes; coord: [8,64,4] i32 (all valid in this dataset, but we honor the mask)

__device__ __forceinline__ float sigmoid_f(float x) {
    return 1.0f / (1.0f + expf(-x));
}
__device__ __forceinline__ float softplus_f(float x) {
    // stable: log(1+e^x) = max(x,0) + log1p(e^{-|x|})
    return fmaxf(x, 0.0f) + log1pf(expf(-fabsf(x)));
}

__global__ void __launch_bounds__(256) neg_loss_kernel(
        const float* __restrict__ logit0, const float* __restrict__ gt0, int n0q,
        const float* __restrict__ logit1, const float* __restrict__ gt1, int n1q,
        float* __restrict__ out) {
    int tid = blockIdx.x * blockDim.x + threadIdx.x;
    int stride = gridDim.x * blockDim.x;
    int total = n0q + n1q;
    float lsum = 0.0f;  // loss_neg with per-level factor baked in
    float csum = 0.0f;  // count_neg (no factor)
    for (int i = tid; i < total; i += stride) {
        const float4* xp; const float4* gp; float f; int j;
        if (i < n0q) { xp = (const float4*)logit0; gp = (const float4*)gt0; f = 2.0f; j = i; }
        else         { xp = (const float4*)logit1; gp = (const float4*)gt1; f = 1.0f; j = i - n0q; }
        float4 x4 = xp[j];
        float4 g4 = gp[j];
        float xs[4] = {x4.x, x4.y, x4.z, x4.w};
        float gs[4] = {g4.x, g4.y, g4.z, g4.w};
        float ll = 0.0f;
        #pragma unroll
        for (int k = 0; k < 4; ++k) {
            float x = xs[k];
            float p = sigmoid_f(x);
            float m = (gs[k] == -1.0f) ? 1.0f : 0.0f;
            float w = p * p * m;          // prob^ALPHA * negmask
            csum += w;
            ll += softplus_f(x) * w;      // nll * w_neg
        }
        lsum += ll * f;
    }
    // wave (64-lane) butterfly reduce
    #pragma unroll
    for (int off = 32; off > 0; off >>= 1) {
        lsum += __shfl_down(lsum, off);
        csum += __shfl_down(csum, off);
    }
    __shared__ float sl[4], sc[4];
    int wave = threadIdx.x >> 6, lane = threadIdx.x & 63;
    if (lane == 0) { sl[wave] = lsum; sc[wave] = csum; }
    __syncthreads();
    if (threadIdx.x == 0) {
        atomicAdd(&out[1], sl[0] + sl[1] + sl[2] + sl[3]);
        atomicAdd(&out[3], sc[0] + sc[1] + sc[2] + sc[3]);
    }
}

// 1024 threads: j in [0,512) -> level0 item j, j in [512,1024) -> level1 item j-512
__global__ void __launch_bounds__(1024) pos_loss_kernel(
        const float* __restrict__ logit0, const int* __restrict__ coord0,
        const float* __restrict__ logit1, const int* __restrict__ coord1,
        float* __restrict__ out) {
    const int j = threadIdx.x;
    float lp = 0.0f, cp = 0.0f;
    {
        const int level = (j >= 512);
        const int jj = level ? (j - 512) : j;
        const int b = jj >> 6;  // P = 64
        const int* cptr = (level ? coord1 : coord0) + jj * 4;
        int c0 = cptr[0], c1 = cptr[1], c2 = cptr[2], c3 = cptr[3];
        const bool v = (c0 > -1);
        const float valid = v ? 1.0f : 0.0f;
        if (!v) { c0 = 0; c1 = 0; c2 = 0; c3 = 0; }
        long off;
        const float* lg;
        float posf;
        if (!level) {
            // [8][2][64][128][128]
            off = ((((long)b * 2 + c0) * 64 + c1) * 128 + c2) * 128 + c3;
            lg = logit0; posf = 2.0f;
        } else {
            // [8][2][32][64][64]
            off = ((((long)b * 2 + c0) * 32 + c1) * 64 + c2) * 64 + c3;
            lg = logit1; posf = 1.0f;
        }
        const float x = lg[off];
        const float p = sigmoid_f(x);
        const float omp = 1.0f - p;
        const float w = omp * omp * valid;         // (1-sigmoid)^ALPHA * valid
        const float w2 = 1.0f;                     // ANCHOR_POS_FACTOR[c0] == 1.0 for both anchors
        const float logsig = -softplus_f(-x);      // log_sigmoid(x)
        lp = -logsig * w * w2 * posf;
        cp = w;
    }
    #pragma unroll
    for (int off = 32; off > 0; off >>= 1) {
        lp += __shfl_down(lp, off);
        cp += __shfl_down(cp, off);
    }
    __shared__ float sl[16], sc[16];
    int wave = threadIdx.x >> 6, lane = threadIdx.x & 63;
    if (lane == 0) { sl[wave] = lp; sc[wave] = cp; }
    __syncthreads();
    if (threadIdx.x == 0) {
        float tl = 0.0f, tc = 0.0f;
        #pragma unroll
        for (int i = 0; i < 16; ++i) { tl += sl[i]; tc += sc[i]; }
        out[0] = tl;  // only writer of these slots; memset ordered before us on stream
        out[2] = tc;
    }
}

extern "C" void kernel_launch(void* const* d_in, const int* in_sizes, int n_in,
                              void* d_out, int out_size, void* d_ws, size_t ws_size,
                              hipStream_t stream) {
    const float* logit0 = (const float*)d_in[0];
    const float* logit1 = (const float*)d_in[1];
    const float* gt0    = (const float*)d_in[2];
    const float* gt1    = (const float*)d_in[3];
    const int*   coord0 = (const int*)d_in[4];
    const int*   coord1 = (const int*)d_in[5];
    float* out = (float*)d_out;

    const int n0 = in_sizes[0];  // 16,777,216
    const int n1 = in_sizes[1];  //  2,097,152
    const int n0q = n0 >> 2;
    const int n1q = n1 >> 2;

    hipMemsetAsync(d_out, 0, out_size * sizeof(float), stream);

    int total_q = n0q + n1q;
    int blocks = (total_q + 255) / 256;
    if (blocks > 2048) blocks = 2048;  // grid-stride; ~8 blocks/CU
    neg_loss_kernel<<<blocks, 256, 0, stream>>>(logit0, gt0, n0q, logit1, gt1, n1q, out);
    pos_loss_kernel<<<1, 1024, 0, stream>>>(logit0, coord0, logit1, coord1, out);
}

// Round 4
// 80.595 us; speedup vs baseline: 1.1217x; 1.1217x over previous
//
#include <hip/hip_runtime.h>

// Focal loss: out[0]=loss_pos, out[1]=loss_neg, out[2]=count_pos, out[3]=count_neg
// ALPHA=2, FPN_POS_FACTOR=(2,1), FPN_NEG_FACTOR=(2,1), ANCHOR_POS_FACTOR={1,1}
// logit0: [8,2,64,128,128] f32, logit1: [8,2,32,64,64] f32
//
// R1: VALUBusy 81% from precise libm. Tolerance ~2% relative -> raw HW trans:
//   v_exp_f32 (exp2 = __builtin_amdgcn_exp2f), v_log_f32 (log2, spelled
//   __builtin_amdgcn_logf!), v_rcp_f32. Work in base-2:
//   z = x*log2e; sigmoid = rcp(1+2^-z); softplus(x) = ln2*(z + log2(1+2^-z))

#define LOG2E 1.44269504088896340736f
#define LN2   0.69314718055994530942f

__device__ __forceinline__ float exp2_hw(float x) { return __builtin_amdgcn_exp2f(x); }
__device__ __forceinline__ float log2_hw(float x) { return __builtin_amdgcn_logf(x); }  // v_log_f32 = log2
__device__ __forceinline__ float rcp_hw(float x)  { return __builtin_amdgcn_rcpf(x); }

// One negative-term element: w = sigmoid(x)^2*[g==-1]; loss += softplus(x)*w
__device__ __forceinline__ void neg_elem(float x, float g, float& lsum, float& csum) {
    float z  = fmaxf(x * LOG2E, -43.0f);    // clamp: below this weight < 1e-26
    float t  = exp2_hw(-z);                 // e^{-x}
    float u  = 1.0f + t;
    float r  = rcp_hw(u);                   // sigmoid(x)
    float w  = (g == -1.0f) ? r * r : 0.0f; // prob^2 * negmask
    float sp = LN2 * (z + log2_hw(u));      // softplus(x), valid for z > -43
    csum += w;
    lsum += sp * w;
}

__global__ void __launch_bounds__(256) neg_loss_kernel(
        const float* __restrict__ logit0, const float* __restrict__ gt0, int n0q,
        const float* __restrict__ logit1, const float* __restrict__ gt1, int n1q,
        float* __restrict__ out) {
    int tid = blockIdx.x * blockDim.x + threadIdx.x;
    int stride = gridDim.x * blockDim.x;
    float l0 = 0.0f, l1 = 0.0f;   // per-level loss sums (factor applied at end)
    float csum = 0.0f;            // count_neg (no factor)

    const float4* x0 = (const float4*)logit0;
    const float4* g0 = (const float4*)gt0;
    for (int i = tid; i < n0q; i += stride) {
        float4 x4 = x0[i];
        float4 g4 = g0[i];
        neg_elem(x4.x, g4.x, l0, csum);
        neg_elem(x4.y, g4.y, l0, csum);
        neg_elem(x4.z, g4.z, l0, csum);
        neg_elem(x4.w, g4.w, l0, csum);
    }
    const float4* x1 = (const float4*)logit1;
    const float4* g1 = (const float4*)gt1;
    for (int i = tid; i < n1q; i += stride) {
        float4 x4 = x1[i];
        float4 g4 = g1[i];
        neg_elem(x4.x, g4.x, l1, csum);
        neg_elem(x4.y, g4.y, l1, csum);
        neg_elem(x4.z, g4.z, l1, csum);
        neg_elem(x4.w, g4.w, l1, csum);
    }
    float lsum = 2.0f * l0 + l1;  // FPN_NEG_FACTOR

    #pragma unroll
    for (int off = 32; off > 0; off >>= 1) {
        lsum += __shfl_down(lsum, off);
        csum += __shfl_down(csum, off);
    }
    __shared__ float sl[4], sc[4];
    int wave = threadIdx.x >> 6, lane = threadIdx.x & 63;
    if (lane == 0) { sl[wave] = lsum; sc[wave] = csum; }
    __syncthreads();
    if (threadIdx.x == 0) {
        atomicAdd(&out[1], sl[0] + sl[1] + sl[2] + sl[3]);
        atomicAdd(&out[3], sc[0] + sc[1] + sc[2] + sc[3]);
    }
}

// 1024 threads: j in [0,512) -> level0 item j, j in [512,1024) -> level1 item j-512
__global__ void __launch_bounds__(1024) pos_loss_kernel(
        const float* __restrict__ logit0, const int* __restrict__ coord0,
        const float* __restrict__ logit1, const int* __restrict__ coord1,
        float* __restrict__ out) {
    const int j = threadIdx.x;
    float lp = 0.0f, cp = 0.0f;
    {
        const int level = (j >= 512);
        const int jj = level ? (j - 512) : j;
        const int b = jj >> 6;  // P = 64
        const int* cptr = (level ? coord1 : coord0) + jj * 4;
        int c0 = cptr[0], c1 = cptr[1], c2 = cptr[2], c3 = cptr[3];
        const bool v = (c0 > -1);
        const float valid = v ? 1.0f : 0.0f;
        if (!v) { c0 = 0; c1 = 0; c2 = 0; c3 = 0; }
        long off;
        const float* lg;
        float posf;
        if (!level) {
            off = ((((long)b * 2 + c0) * 64 + c1) * 128 + c2) * 128 + c3;  // [8][2][64][128][128]
            lg = logit0; posf = 2.0f;
        } else {
            off = ((((long)b * 2 + c0) * 32 + c1) * 64 + c2) * 64 + c3;   // [8][2][32][64][64]
            lg = logit1; posf = 1.0f;
        }
        const float x = lg[off];
        // w = (1-sigmoid(x))^2 * valid;  -log_sigmoid(x) = softplus(-x)
        float z  = fmaxf(-x * LOG2E, -43.0f);
        float t  = exp2_hw(-z);                 // e^{x}
        float u  = 1.0f + t;
        float r  = rcp_hw(u);                   // sigmoid(-x) = 1-p
        float w  = r * r * valid;
        float sp = LN2 * (z + log2_hw(u));      // softplus(-x)
        lp = sp * w * posf;                     // w2 = ANCHOR_POS_FACTOR = 1
        cp = w;
    }
    #pragma unroll
    for (int off = 32; off > 0; off >>= 1) {
        lp += __shfl_down(lp, off);
        cp += __shfl_down(cp, off);
    }
    __shared__ float sl[16], sc[16];
    int wave = threadIdx.x >> 6, lane = threadIdx.x & 63;
    if (lane == 0) { sl[wave] = lp; sc[wave] = cp; }
    __syncthreads();
    if (threadIdx.x == 0) {
        float tl = 0.0f, tc = 0.0f;
        #pragma unroll
        for (int i = 0; i < 16; ++i) { tl += sl[i]; tc += sc[i]; }
        out[0] = tl;
        out[2] = tc;
    }
}

extern "C" void kernel_launch(void* const* d_in, const int* in_sizes, int n_in,
                              void* d_out, int out_size, void* d_ws, size_t ws_size,
                              hipStream_t stream) {
    const float* logit0 = (const float*)d_in[0];
    const float* logit1 = (const float*)d_in[1];
    const float* gt0    = (const float*)d_in[2];
    const float* gt1    = (const float*)d_in[3];
    const int*   coord0 = (const int*)d_in[4];
    const int*   coord1 = (const int*)d_in[5];
    float* out = (float*)d_out;

    const int n0 = in_sizes[0];  // 16,777,216
    const int n1 = in_sizes[1];  //  2,097,152
    const int n0q = n0 >> 2;
    const int n1q = n1 >> 2;

    (void)hipMemsetAsync(d_out, 0, out_size * sizeof(float), stream);

    int total_q = n0q + n1q;
    int blocks = (total_q + 255) / 256;
    if (blocks > 2048) blocks = 2048;  // grid-stride; ~8 blocks/CU
    neg_loss_kernel<<<blocks, 256, 0, stream>>>(logit0, gt0, n0q, logit1, gt1, n1q, out);
    pos_loss_kernel<<<1, 1024, 0, stream>>>(logit0, coord0, logit1, coord1, out);
}